// Round 1
// baseline (256.564 us; speedup 1.0000x reference)
//
#include <hip/hip_runtime.h>

// SSIM 3D loss: pred/target f32 [4,1,64,192,192], scalar output 1 - mean(ssim_map).
// Separable 11-tap Gaussian (sigma=1.5) blur of 5 fields {p, t, p^2, t^2, p*t}:
//   Kernel A: fused W+H blur per (b,d) slice via LDS tiles -> 5 field volumes in ws
//   Kernel B: D blur (register sliding window) + SSIM map + block partial sums
//   Kernel C: final reduction, writes 1 - mean.
// Batch-chunked (G batches/chunk) so ws need is 5*G*VOL*4B (+4KB partials).

#define D_DIM 64
#define H_DIM 192
#define W_DIM 192
#define SLICE (H_DIM * W_DIM)   // 36864
#define VOL   (D_DIM * SLICE)   // 2359296
#define NB    4
#define KS    11
#define RAD   5
#define TH    32
#define TW    32
#define HT    (TH + 2 * RAD)    // 42
#define WT    (TW + 2 * RAD)    // 42
#define C1F   (0.01f * 0.01f)
#define C2F   (0.03f * 0.03f)

__device__ __forceinline__ void make_window(float* g) {
    float s = 0.f;
#pragma unroll
    for (int i = 0; i < KS; ++i) {
        float c = (float)(i - RAD);
        g[i] = expf(-(c * c) * (1.0f / 4.5f));  // 2*sigma^2 = 4.5
        s += g[i];
    }
    float inv = 1.0f / s;
#pragma unroll
    for (int i = 0; i < KS; ++i) g[i] *= inv;
}

// ---- Kernel A: H and W blur of the 5 derived fields for one (b,d) slice tile ----
__global__ __launch_bounds__(256) void hw_blur_kernel(
    const float* __restrict__ pred, const float* __restrict__ targ,
    float* __restrict__ fields, int b0, int gvol) {
    __shared__ float sp[HT * WT];
    __shared__ float st[HT * WT];
    __shared__ float interm[5 * HT * TW];

    float g[KS];
    make_window(g);

    const int tid = threadIdx.x;
    const int d    = blockIdx.y;
    const int tile = blockIdx.x;              // 0..35
    const int h0 = (tile / 6) * TH;
    const int w0 = (tile % 6) * TW;
    const int bl = blockIdx.z;                // local batch within chunk

    const int in_base = (b0 + bl) * VOL + d * SLICE;

    // Stage p/t halo tiles (zero-padded at H/W edges)
    for (int i = tid; i < HT * WT; i += 256) {
        int y = i / WT, x = i - y * WT;
        int gh = h0 + y - RAD, gw = w0 + x - RAD;
        float pv = 0.f, tv = 0.f;
        if ((unsigned)gh < (unsigned)H_DIM && (unsigned)gw < (unsigned)W_DIM) {
            int idx = in_base + gh * W_DIM + gw;
            pv = pred[idx];
            tv = targ[idx];
        }
        sp[i] = pv;
        st[i] = tv;
    }
    __syncthreads();

    // Blur along W; derive the 5 fields on the fly
    for (int i = tid; i < HT * TW; i += 256) {
        int y = i / TW, x = i - y * TW;
        float s0 = 0.f, s1 = 0.f, s2 = 0.f, s3 = 0.f, s4 = 0.f;
        int row = y * WT + x;
#pragma unroll
        for (int k = 0; k < KS; ++k) {
            float pv = sp[row + k];
            float tv = st[row + k];
            float gk = g[k];
            s0 += gk * pv;
            s1 += gk * tv;
            s2 += gk * pv * pv;
            s3 += gk * tv * tv;
            s4 += gk * pv * tv;
        }
        interm[0 * HT * TW + i] = s0;
        interm[1 * HT * TW + i] = s1;
        interm[2 * HT * TW + i] = s2;
        interm[3 * HT * TW + i] = s3;
        interm[4 * HT * TW + i] = s4;
    }
    __syncthreads();

    // Blur along H, store 5 fields
    const int out_base = bl * VOL + d * SLICE;
    for (int i = tid; i < TH * TW; i += 256) {
        int y = i / TW, x = i - y * TW;
        float s0 = 0.f, s1 = 0.f, s2 = 0.f, s3 = 0.f, s4 = 0.f;
#pragma unroll
        for (int k = 0; k < KS; ++k) {
            float gk = g[k];
            int base = (y + k) * TW + x;
            s0 += gk * interm[0 * HT * TW + base];
            s1 += gk * interm[1 * HT * TW + base];
            s2 += gk * interm[2 * HT * TW + base];
            s3 += gk * interm[3 * HT * TW + base];
            s4 += gk * interm[4 * HT * TW + base];
        }
        int o = out_base + (h0 + y) * W_DIM + (w0 + x);
        fields[o]            = s0;
        fields[gvol + o]     = s1;
        fields[2 * gvol + o] = s2;
        fields[3 * gvol + o] = s3;
        fields[4 * gvol + o] = s4;
    }
}

// ---- Kernel B: D blur (sliding register window) + SSIM + per-block partial sum ----
__global__ __launch_bounds__(256) void dblur_ssim_kernel(
    const float* __restrict__ fields, float* __restrict__ partials,
    int gvol, int ncols) {
    float g[KS];
    make_window(g);

    const int tid = threadIdx.x;
    const int col = blockIdx.x * 256 + tid;
    float acc = 0.f;

    if (col < ncols) {
        const int bl = col / SLICE;
        const int hw = col - bl * SLICE;
        const int cb = bl * VOL + hw;

        // win[f][j] holds plane (d - 6 + j) at loop top for iteration d
        float win[5][KS];
#pragma unroll
        for (int f = 0; f < 5; ++f)
#pragma unroll
            for (int j = 0; j < KS; ++j) win[f][j] = 0.f;

        // preload planes 0..4 into j = 6..10  (positions d-6+j for d=0)
#pragma unroll
        for (int j = RAD + 1; j < KS; ++j) {
            int dp = j - (RAD + 1);  // 0..4
#pragma unroll
            for (int f = 0; f < 5; ++f)
                win[f][j] = fields[f * gvol + cb + dp * SLICE];
        }

        for (int d = 0; d < D_DIM; ++d) {
            // shift left
#pragma unroll
            for (int f = 0; f < 5; ++f)
#pragma unroll
                for (int j = 0; j < KS - 1; ++j) win[f][j] = win[f][j + 1];
            // load plane d+5 (zero past the end)
            int dn = d + RAD;
            if (dn < D_DIM) {
                int off = cb + dn * SLICE;
#pragma unroll
                for (int f = 0; f < 5; ++f) win[f][KS - 1] = fields[f * gvol + off];
            } else {
#pragma unroll
                for (int f = 0; f < 5; ++f) win[f][KS - 1] = 0.f;
            }
            // dot with window
            float mu_p = 0.f, mu_t = 0.f, ep2 = 0.f, et2 = 0.f, ept = 0.f;
#pragma unroll
            for (int j = 0; j < KS; ++j) {
                float gj = g[j];
                mu_p += gj * win[0][j];
                mu_t += gj * win[1][j];
                ep2  += gj * win[2][j];
                et2  += gj * win[3][j];
                ept  += gj * win[4][j];
            }
            float mu_p_sq = mu_p * mu_p;
            float mu_t_sq = mu_t * mu_t;
            float mu_pt   = mu_p * mu_t;
            float sig_p   = ep2 - mu_p_sq;
            float sig_t   = et2 - mu_t_sq;
            float sig_pt  = ept - mu_pt;
            float num = (2.f * mu_pt + C1F) * (2.f * sig_pt + C2F);
            float den = (mu_p_sq + mu_t_sq + C1F) * (sig_p + sig_t + C2F);
            acc += num / den;
        }
    }

    // block reduction
#pragma unroll
    for (int off = 32; off > 0; off >>= 1) acc += __shfl_down(acc, off, 64);
    __shared__ float red[4];
    int lane = tid & 63, wv = tid >> 6;
    if (lane == 0) red[wv] = acc;
    __syncthreads();
    if (tid == 0) partials[blockIdx.x] = red[0] + red[1] + red[2] + red[3];
}

// ---- Kernel C: final reduction ----
__global__ __launch_bounds__(256) void finalize_kernel(
    const float* __restrict__ partials, int n, float* __restrict__ out) {
    double a = 0.0;
    for (int i = threadIdx.x; i < n; i += 256) a += (double)partials[i];
#pragma unroll
    for (int off = 32; off > 0; off >>= 1) a += __shfl_down(a, off, 64);
    __shared__ double red[4];
    int lane = threadIdx.x & 63, wv = threadIdx.x >> 6;
    if (lane == 0) red[wv] = a;
    __syncthreads();
    if (threadIdx.x == 0) {
        double s = red[0] + red[1] + red[2] + red[3];
        out[0] = (float)(1.0 - s / (double)((long long)NB * VOL));
    }
}

extern "C" void kernel_launch(void* const* d_in, const int* in_sizes, int n_in,
                              void* d_out, int out_size, void* d_ws, size_t ws_size,
                              hipStream_t stream) {
    const float* pred = (const float*)d_in[0];
    const float* targ = (const float*)d_in[1];
    float* out = (float*)d_out;
    float* ws  = (float*)d_ws;

    // choose batches-per-chunk G in {4,2,1} that fits ws
    const size_t partial_bytes = 1024 * sizeof(float);
    int G = 4;
    while (G > 1 && (size_t)5 * G * VOL * sizeof(float) + partial_bytes > ws_size) G >>= 1;

    const int gvol = G * VOL;
    float* partials = ws + (size_t)5 * gvol;  // fixed across chunks (G constant)
    const int blocks_per_chunk = G * (SLICE / 256);  // G * 144
    const int nchunks = NB / G;

    for (int c = 0; c < nchunks; ++c) {
        int b0 = c * G;
        hw_blur_kernel<<<dim3(36, D_DIM, G), 256, 0, stream>>>(pred, targ, ws, b0, gvol);
        dblur_ssim_kernel<<<dim3(blocks_per_chunk), 256, 0, stream>>>(
            ws, partials + c * blocks_per_chunk, gvol, G * SLICE);
    }
    finalize_kernel<<<1, 256, 0, stream>>>(partials, NB * (SLICE / 256), out);
}